// Round 1
// baseline (163.838 us; speedup 1.0000x reference)
//
#include <hip/hip_runtime.h>
#include <math.h>

namespace {

constexpr int W_TS = 256, NE = 16, NB = 512, NI = 10, NF = 3;
constexpr int BI   = NB * NI;          // 5120
constexpr int PROJ = 7, IN_P = 4, EMB = 32, NTOT = 79;
constexpr int BLK  = 64;               // 1 wave per block -> 1280 blocks = 5 waves/CU, balanced
constexpr int PFK  = 8;                // prefetch depth (W_TS % PFK == 0)
constexpr float MAX_RATIO    = 0.5f;
constexpr float INV_SQRT_DEG = 0.70710678118654752440f;

__device__ __forceinline__ float gelu_exact(float x) {
  return 0.5f * x * (1.0f + erff(x * 0.70710678118654752440f));
}

// Compute one offset group (rows [OB, OB+N) of hW_out @ h1 + hb_out),
// apply the norm-ball constraint against the group's reference weights,
// and write the effective per-thread weights. All indices compile-time.
template<int N, int OB>
__device__ __forceinline__ void constrain_group(
    const float* __restrict__ Wo,   // hW_out for this e: (79,32)
    const float* __restrict__ bo,   // hb_out for this e: (79)
    const float* __restrict__ h1,   // hidden activations (32, regs)
    const float* __restrict__ refw, // group reference weights (N, uniform per e)
    float* __restrict__ outw)       // N effective weights (regs)
{
  float off[N];
  float ss = 0.f;
#pragma unroll
  for (int n = 0; n < N; ++n) {
    float acc = bo[OB + n];
#pragma unroll
    for (int i = 0; i < EMB; ++i)
      acc = fmaf(Wo[(OB + n) * EMB + i], h1[i], acc);
    off[n] = acc;
    ss = fmaf(acc, acc, ss);
  }
  float rn = 0.f;
#pragma unroll
  for (int n = 0; n < N; ++n) { float w = refw[n]; rn = fmaf(w, w, rn); }
  float max_norm = fmaxf(sqrtf(rn) * MAX_RATIO, 0.01f);
  float scale    = fminf(max_norm / (sqrtf(ss) + 1e-8f), 1.0f);
#pragma unroll
  for (int n = 0; n < N; ++n) outw[n] = refw[n] + off[n] * scale;
}

__global__ __launch_bounds__(BLK)
void ensemble_rnn(const float* __restrict__ xin,       // (W_TS,E,BI,F)
                  const float* __restrict__ h0,        // (E,BI)
                  const float* __restrict__ embedding, // (E,NB,EMB)
                  const float* __restrict__ w0g,       // (E,7,4)
                  const float* __restrict__ w1g,       // (E,7,4)
                  const float* __restrict__ b0g,       // (E,7)
                  const float* __restrict__ b1g,       // (E,7)
                  const float* __restrict__ wng,       // (E,1,7)
                  const float* __restrict__ bng,       // (E,1)
                  const float* __restrict__ damping,   // (E)
                  const float* __restrict__ hW_in,     // (E,32,32)
                  const float* __restrict__ hb_in,     // (E,32)
                  const float* __restrict__ hW_out,    // (E,79,32)
                  const float* __restrict__ hb_out,    // (E,79)
                  float* __restrict__ out)             // (W_TS,E,BI)
{
  constexpr int BLOCKS_PER_E = BI / BLK;  // 80 -> e is block-uniform (scalar loads)
  const int e  = blockIdx.x / BLOCKS_PER_E;
  const int bi = (blockIdx.x % BLOCKS_PER_E) * BLK + (int)threadIdx.x;
  const int b  = bi / NI;

  // ---------------- hypernetwork (runs once per thread) ----------------
  float emb[EMB];
  {
    const float4* ep =
        reinterpret_cast<const float4*>(embedding + ((size_t)e * NB + b) * EMB);
#pragma unroll
    for (int i = 0; i < EMB / 4; ++i) {
      float4 v = ep[i];
      emb[4*i+0] = v.x; emb[4*i+1] = v.y; emb[4*i+2] = v.z; emb[4*i+3] = v.w;
    }
  }

  float h1[EMB];
  {
    const float* Wi = hW_in + (size_t)e * EMB * EMB;
    const float* bb = hb_in + (size_t)e * EMB;
#pragma unroll
    for (int o = 0; o < EMB; ++o) {
      float acc = bb[o];
#pragma unroll
      for (int i = 0; i < EMB; ++i) acc = fmaf(Wi[o * EMB + i], emb[i], acc);
      h1[o] = gelu_exact(acc);
    }
  }

  const float* Wo = hW_out + (size_t)e * NTOT * EMB;
  const float* bo = hb_out + (size_t)e * NTOT;

  float w0e[PROJ * IN_P], w1e[PROJ * IN_P];
  float b0e[PROJ], b1e[PROJ], wns[PROJ], bne;

  constrain_group<28, 0 >(Wo, bo, h1, w0g + e * 28, w0e);
  constrain_group<28, 28>(Wo, bo, h1, w1g + e * 28, w1e);
  constrain_group<7,  56>(Wo, bo, h1, b0g + e * 7,  b0e);
  constrain_group<7,  63>(Wo, bo, h1, b1g + e * 7,  b1e);
  constrain_group<7,  70>(Wo, bo, h1, wng + e * 7,  wns);
  constrain_group<1,  77>(Wo, bo, h1, bng + e,      &bne);

  // fold 1/sqrt(DEG) into the readout weights
#pragma unroll
  for (int o = 0; o < PROJ; ++o) wns[o] *= INV_SQRT_DEG;

  const float dec = 1.0f / (1.0f + expf(-damping[e]));
  const float omd = 1.0f - dec;

  // ---------------- RNN scan (hot loop) ----------------
  float h = h0[(size_t)e * BI + bi];

  const float* xbase = xin + ((size_t)e * BI + bi) * NF;  // t=0 element
  constexpr size_t TSTRIDE_IN  = (size_t)NE * BI * NF;    // floats per timestep
  constexpr size_t TSTRIDE_OUT = (size_t)NE * BI;
  float* obase = out + (size_t)e * BI + bi;

  // register prefetch pipeline, all statically indexed
  float xb[PFK][NF];
#pragma unroll
  for (int k = 0; k < PFK; ++k) {
    const float* p = xbase + (size_t)k * TSTRIDE_IN;
    xb[k][0] = p[0]; xb[k][1] = p[1]; xb[k][2] = p[2];
  }

  for (int tc = 0; tc < W_TS; tc += PFK) {
#pragma unroll
    for (int k = 0; k < PFK; ++k) {
      const int t = tc + k;
      const float x0 = xb[k][0], x1 = xb[k][1], x2 = xb[k][2];

      // issue prefetch for t+PFK (wave-uniform branch)
      const int tn = t + PFK;
      if (tn < W_TS) {
        const float* p = xbase + (size_t)tn * TSTRIDE_IN;
        xb[k][0] = p[0]; xb[k][1] = p[1]; xb[k][2] = p[2];
      }

      float delta = bne;
#pragma unroll
      for (int o = 0; o < PROJ; ++o) {
        float a = b0e[o];
        a = fmaf(w0e[o*4+0], x0, a);
        a = fmaf(w0e[o*4+1], x1, a);
        a = fmaf(w0e[o*4+2], x2, a);
        a = fmaf(w0e[o*4+3], h,  a);
        float c = b1e[o];
        c = fmaf(w1e[o*4+0], x0, c);
        c = fmaf(w1e[o*4+1], x1, c);
        c = fmaf(w1e[o*4+2], x2, c);
        c = fmaf(w1e[o*4+3], h,  c);
        delta = fmaf(wns[o], a * c, delta);
      }
      h = fmaf(h, omd, delta);
      obase[(size_t)t * TSTRIDE_OUT] = h;
    }
  }
}

} // anonymous namespace

extern "C" void kernel_launch(void* const* d_in, const int* in_sizes, int n_in,
                              void* d_out, int out_size, void* d_ws, size_t ws_size,
                              hipStream_t stream) {
  const float* xin  = (const float*)d_in[0];
  const float* h0   = (const float*)d_in[1];
  const float* emb  = (const float*)d_in[2];
  const float* w0   = (const float*)d_in[3];
  const float* w1   = (const float*)d_in[4];
  const float* b0   = (const float*)d_in[5];
  const float* b1   = (const float*)d_in[6];
  const float* wn   = (const float*)d_in[7];
  const float* bn   = (const float*)d_in[8];
  const float* damp = (const float*)d_in[9];
  const float* hWi  = (const float*)d_in[10];
  const float* hbi  = (const float*)d_in[11];
  const float* hWo  = (const float*)d_in[12];
  const float* hbo  = (const float*)d_in[13];
  float* out = (float*)d_out;

  dim3 grid(NE * BI / BLK);   // 1280 blocks
  dim3 block(BLK);            // 64 threads = 1 wave
  hipLaunchKernelGGL(ensemble_rnn, grid, block, 0, stream,
                     xin, h0, emb, w0, w1, b0, b1, wn, bn, damp,
                     hWi, hbi, hWo, hbo, out);
}